// Round 1
// 1067.913 us; speedup vs baseline: 1.1652x; 1.1652x over previous
//
#include <hip/hip_runtime.h>
#include <hip/hip_bf16.h>

#define NN 500000
#define EE 2000000
#define GG 16384
#define ND 44
#define ED 12
#define HH 64
#define EMB 128
#define NBLK 123          // ceil(NN / 4096) scan blocks

typedef __attribute__((ext_vector_type(8))) short bf16x8;
typedef __attribute__((ext_vector_type(4))) float f32x4;

// fp32 -> bf16 round-to-nearest-even, bit pattern as short
__device__ inline short f2bf(float v) {
    unsigned int x = __builtin_bit_cast(unsigned int, v);
    x += 0x7FFFu + ((x >> 16) & 1u);
    return (short)(x >> 16);
}

// ---------------------------------------------------------------------------
// Weight prep: transpose to [n][k] layout, cast to bf16, zero-pad K of w1a to 64
__global__ __launch_bounds__(256) void prep_weights(
    const float* __restrict__ w1a, const float* __restrict__ w1b,
    const float* __restrict__ w2a, const float* __restrict__ w2b,
    short* __restrict__ o) {
    int t = blockIdx.x * 256 + threadIdx.x;
    if (t < 4096) {
        int n = t >> 6, k = t & 63;
        o[t] = f2bf(k < ND ? w1a[k * HH + n] : 0.f);
    } else if (t < 8192) {
        int u = t - 4096; int n = u >> 6, k = u & 63;
        o[t] = f2bf(w1b[k * HH + n]);
    } else if (t < 16384) {
        int u = t - 8192; int n = u >> 6, k = u & 63;
        o[t] = f2bf(w2a[k * EMB + n]);
    } else if (t < 32768) {
        int u = t - 16384; int n = u >> 7, k = u & 127;
        o[t] = f2bf(w2b[k * EMB + n]);
    }
}

// ---------------------------------------------------------------------------
// CSR build: histogram of dst, exclusive scan, scatter by dst.
__global__ __launch_bounds__(256) void hist_kernel(const int* __restrict__ ei,
                                                   int* __restrict__ deg) {
    int e = blockIdx.x * 256 + threadIdx.x;
    if (e < EE) atomicAdd(&deg[ei[EE + e]], 1);
}

__global__ __launch_bounds__(256) void scan_reduce(const int* __restrict__ deg,
                                                   int* __restrict__ bsum) {
    int b = blockIdx.x, t = threadIdx.x;
    int base = b * 4096;
    int s = 0;
    for (int i = t; i < 4096; i += 256) {
        int g = base + i;
        if (g < NN) s += deg[g];
    }
#pragma unroll
    for (int off = 32; off; off >>= 1) s += __shfl_xor(s, off);
    __shared__ int ws[4];
    if ((t & 63) == 0) ws[t >> 6] = s;
    __syncthreads();
    if (t == 0) bsum[b] = ws[0] + ws[1] + ws[2] + ws[3];
}

__global__ __launch_bounds__(128) void scan_mid(const int* __restrict__ bsum,
                                                int* __restrict__ boff,
                                                int* __restrict__ rowptr) {
    int t = threadIdx.x;
    int v = (t < NBLK) ? bsum[t] : 0;
    int x = v;
#pragma unroll
    for (int off = 1; off < 64; off <<= 1) {
        int y = __shfl_up(x, off);
        if ((t & 63) >= off) x += y;
    }
    __shared__ int wt[2];
    if ((t & 63) == 63) wt[t >> 6] = x;
    __syncthreads();
    int xx = x + ((t >= 64) ? wt[0] : 0);
    if (t < NBLK) boff[t] = xx - v;
    if (t == 127) rowptr[NN] = xx;
}

__global__ __launch_bounds__(256) void scan_final(const int* __restrict__ deg,
                                                  const int* __restrict__ boff,
                                                  int* __restrict__ rowptr,
                                                  int* __restrict__ cursor) {
    int b = blockIdx.x, t = threadIdx.x;
    int base = b * 4096 + t * 16;
    int loc[16];
    int s = 0;
#pragma unroll
    for (int j = 0; j < 16; ++j) {
        int g = base + j;
        loc[j] = (g < NN) ? deg[g] : 0;
        s += loc[j];
    }
    int xinc = s;
#pragma unroll
    for (int off = 1; off < 64; off <<= 1) {
        int y = __shfl_up(xinc, off);
        if ((t & 63) >= off) xinc += y;
    }
    __shared__ int wt[4];
    if ((t & 63) == 63) wt[t >> 6] = xinc;
    __syncthreads();
    int wv = t >> 6, woff = 0;
#pragma unroll
    for (int k = 0; k < 4; ++k)
        if (k < wv) woff += wt[k];
    int run = boff[b] + woff + (xinc - s);
#pragma unroll
    for (int j = 0; j < 16; ++j) {
        int g = base + j;
        if (g < NN) { rowptr[g] = run; cursor[g] = run; }
        run += loc[j];
    }
}

// Scatter: besides src, also reorder the 48B edge-attr row into CSR (dst-sorted)
// order so agg_gather reads attrs SEQUENTIALLY instead of random-by-eid.
__global__ __launch_bounds__(256) void scatter_kernel(const int* __restrict__ ei,
                                                      const float* __restrict__ ea,
                                                      int* __restrict__ cursor,
                                                      int* __restrict__ csr_src,
                                                      float* __restrict__ csr_ea) {
    int e = blockIdx.x * 256 + threadIdx.x;
    if (e < EE) {
        int dst = ei[EE + e];
        const float4* s = (const float4*)(ea + (size_t)e * ED);
        float4 a0 = s[0], a1 = s[1], a2 = s[2];
        int pos = atomicAdd(&cursor[dst], 1);
        csr_src[pos] = ei[e];
        float4* d = (float4*)(csr_ea + (size_t)pos * ED);
        d[0] = a0; d[1] = a1; d[2] = a2;
    }
}

// ---------------------------------------------------------------------------
// Gather aggregation, 8 nodes/wave, with FUSED skip-add + bf16 output:
//   out16[i][0:64] = bf16( xf[i] + sum_{e: dst=i} relu(xf[src] + ea@W + b) )
// (zero-padded to 64 cols for D=44; bit-identical to the old f32 path because
//  the skip add was previously done in f32 inside the MLP right before f2bf).
// Edge attrs come from csr_ea (CSR order -> sequential reads, L2-resident);
// the only remaining random access per edge is the xf[src] row gather.
template <int D>
__global__ __launch_bounds__(256) void agg_gather(
    const float* __restrict__ xf, const float* __restrict__ cea,
    const float* __restrict__ ew, const float* __restrict__ eb,
    const int* __restrict__ rowptr, const int* __restrict__ csr_src,
    short* __restrict__ out) {
    int lane = threadIdx.x & 63;
    int wv = threadIdx.x >> 6;
    int i0 = (blockIdx.x * 4 + wv) * 8;
    if (i0 >= NN) return;
    float w0, w1, w2, w3, w4, w5, w6, w7, w8, w9, w10, w11, breg;
    if (D == 64 || lane < D) {
        w0 = ew[0 * D + lane];  w1 = ew[1 * D + lane];  w2 = ew[2 * D + lane];
        w3 = ew[3 * D + lane];  w4 = ew[4 * D + lane];  w5 = ew[5 * D + lane];
        w6 = ew[6 * D + lane];  w7 = ew[7 * D + lane];  w8 = ew[8 * D + lane];
        w9 = ew[9 * D + lane];  w10 = ew[10 * D + lane]; w11 = ew[11 * D + lane];
        breg = eb[lane];
    } else {
        w0=w1=w2=w3=w4=w5=w6=w7=w8=w9=w10=w11=0.f; breg = 0.f;
    }
    int rp = (lane <= 8) ? rowptr[i0 + lane] : 0;
    int beg = __builtin_amdgcn_readfirstlane(__builtin_amdgcn_readlane(rp, 0));
    int end = __builtin_amdgcn_readfirstlane(__builtin_amdgcn_readlane(rp, 8));
    // coalesced preload of this wave's CSR src span (first 128 entries)
    int s0 = 0, s1 = 0;
    if (beg + lane < end) s0 = csr_src[beg + lane];
    if (beg + 64 + lane < end) s1 = csr_src[beg + 64 + lane];

    auto SKIPLD = [&](int j) -> float {
        return (D == 64 || lane < D) ? xf[(size_t)(i0 + j) * D + lane] : 0.f;
    };

    float acc = 0.f;
    int np = 0;
    int nb = __builtin_amdgcn_readlane(rp, 1);
    float sk = SKIPLD(0);   // skip row for current node, prefetched early
    // FIX (r4 bug): flush leading empty nodes (boundary == beg). Without this,
    // a wave whose first node has zero in-edges never matches p1==nb and all
    // 8 node rows got zeroed by the tail loop.
    while (np < 8 && nb == beg) {
        out[(size_t)(i0 + np) * 64 + lane] = f2bf(sk);   // acc == 0
        ++np;
        nb = (np < 8) ? __builtin_amdgcn_readlane(rp, np + 1) : 0x7fffffff;
        sk = (np < 8) ? SKIPLD(np) : 0.f;
    }

    auto LOADE = [&](int pos, float4& E0, float4& E1, float4& E2, float& XV) {
        if (pos < end) {
            int off = pos - beg;
            int src;
            if (off < 64)       src = __builtin_amdgcn_readlane(s0, off);
            else if (off < 128) src = __builtin_amdgcn_readlane(s1, off - 64);
            else                src = __builtin_amdgcn_readfirstlane(csr_src[pos]);
            const float4* ep = (const float4*)(cea + (size_t)pos * ED);
            E0 = ep[0]; E1 = ep[1]; E2 = ep[2];
            if (D == 64) XV = xf[(size_t)src * D + lane];
            else         XV = (lane < D) ? xf[(size_t)src * D + lane] : 0.f;
        }
    };
    auto CONSUME = [&](int pos, const float4& E0, const float4& E1,
                       const float4& E2, float XV) {
        if (pos < end) {
            float elin = breg;
            elin = fmaf(E0.x, w0, elin);  elin = fmaf(E0.y, w1, elin);
            elin = fmaf(E0.z, w2, elin);  elin = fmaf(E0.w, w3, elin);
            elin = fmaf(E1.x, w4, elin);  elin = fmaf(E1.y, w5, elin);
            elin = fmaf(E1.z, w6, elin);  elin = fmaf(E1.w, w7, elin);
            elin = fmaf(E2.x, w8, elin);  elin = fmaf(E2.y, w9, elin);
            elin = fmaf(E2.z, w10, elin); elin = fmaf(E2.w, w11, elin);
            acc += fmaxf(XV + elin, 0.f);
            int p1 = pos + 1;
            if (p1 == nb) {
                do {
                    out[(size_t)(i0 + np) * 64 + lane] = f2bf(acc + sk);
                    acc = 0.f; ++np;
                    nb = (np < 8) ? __builtin_amdgcn_readlane(rp, np + 1) : 0x7fffffff;
                    sk = (np < 8) ? SKIPLD(np) : 0.f;
                } while (p1 == nb);
            }
        }
    };

    float4 A0, A1, A2, B0, B1, B2, C0, C1, C2, D0, D1, D2;
    float Ax = 0.f, Bx = 0.f, Cx = 0.f, Dx = 0.f;
    int base = beg;
    LOADE(base + 0, A0, A1, A2, Ax);
    LOADE(base + 1, B0, B1, B2, Bx);
    LOADE(base + 2, C0, C1, C2, Cx);
    LOADE(base + 3, D0, D1, D2, Dx);
    while (base < end) {
        CONSUME(base + 0, A0, A1, A2, Ax);
        CONSUME(base + 1, B0, B1, B2, Bx);
        LOADE(base + 4, A0, A1, A2, Ax);
        LOADE(base + 5, B0, B1, B2, Bx);
        if (base + 2 >= end) break;
        CONSUME(base + 2, C0, C1, C2, Cx);
        CONSUME(base + 3, D0, D1, D2, Dx);
        LOADE(base + 6, C0, C1, C2, Cx);
        LOADE(base + 7, D0, D1, D2, Dx);
        base += 4;
    }
}

// ---------------------------------------------------------------------------
// Node MLP 1: h = relu( relu(a @ w1a + b1a) @ w1b + b1b ), a = bf16[N][64] in
#define HSTR1 68
__global__ __launch_bounds__(256) void mlp1(
    const short* __restrict__ ain,
    const short* __restrict__ w1a_t, const float* __restrict__ b1a,
    const short* __restrict__ w1b_t, const float* __restrict__ b1b,
    float* __restrict__ h) {
    __shared__ float hid[4][16 * HSTR1];
    int lane = threadIdx.x & 63;
    int wv = threadIdx.x >> 6;
    int tile = blockIdx.x * 4 + wv;
    bool act = tile < (NN / 16);
    int tile_c = act ? tile : (NN / 16 - 1);
    int node0 = tile_c * 16;
    int mrow = lane & 15, q = lane >> 4;
    int m = node0 + mrow;
    float* hw = hid[wv];

    bf16x8 afrag[2];
    afrag[0] = *(const bf16x8*)(ain + (size_t)m * 64 + q * 8);
    afrag[1] = *(const bf16x8*)(ain + (size_t)m * 64 + 32 + q * 8);
#pragma unroll
    for (int nt = 0; nt < 4; ++nt) {
        int n = nt * 16 + mrow;
        float bias = b1a[n];
        f32x4 acc = {bias, bias, bias, bias};
#pragma unroll
        for (int s = 0; s < 2; ++s) {
            bf16x8 bfrag = *(const bf16x8*)(w1a_t + n * 64 + s * 32 + q * 8);
            acc = __builtin_amdgcn_mfma_f32_16x16x32_bf16(afrag[s], bfrag, acc, 0, 0, 0);
        }
#pragma unroll
        for (int r = 0; r < 4; ++r)
            hw[(q * 4 + r) * HSTR1 + n] = fmaxf(acc[r], 0.f);
    }
    __syncthreads();
    bf16x8 af2[2];
#pragma unroll
    for (int s = 0; s < 2; ++s) {
        f32x4 v0 = *(const f32x4*)(hw + mrow * HSTR1 + s * 32 + q * 8);
        f32x4 v1 = *(const f32x4*)(hw + mrow * HSTR1 + s * 32 + q * 8 + 4);
#pragma unroll
        for (int j = 0; j < 4; ++j) { af2[s][j] = f2bf(v0[j]); af2[s][j + 4] = f2bf(v1[j]); }
    }
#pragma unroll
    for (int nt = 0; nt < 4; ++nt) {
        int n = nt * 16 + mrow;
        float bias = b1b[n];
        f32x4 acc = {bias, bias, bias, bias};
#pragma unroll
        for (int s = 0; s < 2; ++s) {
            bf16x8 bfrag = *(const bf16x8*)(w1b_t + n * 64 + s * 32 + q * 8);
            acc = __builtin_amdgcn_mfma_f32_16x16x32_bf16(af2[s], bfrag, acc, 0, 0, 0);
        }
        if (act) {
#pragma unroll
            for (int r = 0; r < 4; ++r)
                h[(node0 + q * 4 + r) * HH + n] = fmaxf(acc[r], 0.f);
        }
    }
}

// ---------------------------------------------------------------------------
// Node MLP 2 + fused mean-pool accumulate: input = bf16[N][64] (h+agg2 fused)
#define HSTR2 132
__global__ __launch_bounds__(256) void mlp2(
    const short* __restrict__ ain,
    const short* __restrict__ w2a_t, const float* __restrict__ b2a,
    const short* __restrict__ w2b_t, const float* __restrict__ b2b,
    const int* __restrict__ batch, float* __restrict__ sums) {
    __shared__ float buf[4][16 * HSTR2];
    int lane = threadIdx.x & 63;
    int wv = threadIdx.x >> 6;
    int tile = blockIdx.x * 4 + wv;
    bool act = tile < (NN / 16);
    int tile_c = act ? tile : (NN / 16 - 1);
    int node0 = tile_c * 16;
    int mrow = lane & 15, q = lane >> 4;
    int m = node0 + mrow;
    float* bw = buf[wv];

    bf16x8 afrag[2];
    afrag[0] = *(const bf16x8*)(ain + (size_t)m * 64 + q * 8);
    afrag[1] = *(const bf16x8*)(ain + (size_t)m * 64 + 32 + q * 8);
#pragma unroll
    for (int nt = 0; nt < 8; ++nt) {
        int n = nt * 16 + mrow;
        float bias = b2a[n];
        f32x4 acc = {bias, bias, bias, bias};
#pragma unroll
        for (int s = 0; s < 2; ++s) {
            bf16x8 bfrag = *(const bf16x8*)(w2a_t + n * HH + s * 32 + q * 8);
            acc = __builtin_amdgcn_mfma_f32_16x16x32_bf16(afrag[s], bfrag, acc, 0, 0, 0);
        }
#pragma unroll
        for (int r = 0; r < 4; ++r)
            bw[(q * 4 + r) * HSTR2 + n] = fmaxf(acc[r], 0.f);
    }
    __syncthreads();
    bf16x8 af2[4];
#pragma unroll
    for (int s = 0; s < 4; ++s) {
        f32x4 v0 = *(const f32x4*)(bw + mrow * HSTR2 + s * 32 + q * 8);
        f32x4 v1 = *(const f32x4*)(bw + mrow * HSTR2 + s * 32 + q * 8 + 4);
#pragma unroll
        for (int j = 0; j < 4; ++j) { af2[s][j] = f2bf(v0[j]); af2[s][j + 4] = f2bf(v1[j]); }
    }
    __syncthreads();
    f32x4 oacc[8];
#pragma unroll
    for (int nt = 0; nt < 8; ++nt) {
        int n = nt * 16 + mrow;
        float bias = b2b[n];
        f32x4 acc = {bias, bias, bias, bias};
#pragma unroll
        for (int s = 0; s < 4; ++s) {
            bf16x8 bfrag = *(const bf16x8*)(w2b_t + n * EMB + s * 32 + q * 8);
            acc = __builtin_amdgcn_mfma_f32_16x16x32_bf16(af2[s], bfrag, acc, 0, 0, 0);
        }
        oacc[nt] = acc;
    }
#pragma unroll
    for (int nt = 0; nt < 8; ++nt)
#pragma unroll
        for (int r = 0; r < 4; ++r)
            bw[(q * 4 + r) * HSTR2 + nt * 16 + mrow] = oacc[nt][r];
    __syncthreads();
    int bv = (act && lane < 16) ? batch[node0 + lane] : 0;
    if (act) {
#pragma unroll
        for (int cp = 0; cp < 2; ++cp) {
            int col = lane + cp * 64;
            float run = 0.f;
            int bprev = __shfl(bv, 0);
            for (int i = 0; i < 16; ++i) {
                int bg = __shfl(bv, i);
                if (bg != bprev) {
                    atomicAdd(&sums[bprev * EMB + col], run);
                    run = 0.f; bprev = bg;
                }
                run += bw[i * HSTR2 + col];
            }
            atomicAdd(&sums[bprev * EMB + col], run);
        }
    }
}

// ---------------------------------------------------------------------------
__global__ __launch_bounds__(128) void finalize(
    const float* __restrict__ sums, const int* __restrict__ batch,
    float* __restrict__ out) {
    int g = blockIdx.x;
    __shared__ int cnt_s;
    if (threadIdx.x == 0) {
        int lo = 0, hi = NN;
        while (lo < hi) { int mid = (lo + hi) >> 1; if (batch[mid] < g) lo = mid + 1; else hi = mid; }
        int lo2 = lo, hi2 = NN;
        while (lo2 < hi2) { int mid = (lo2 + hi2) >> 1; if (batch[mid] < g + 1) lo2 = mid + 1; else hi2 = mid; }
        cnt_s = lo2 - lo;
    }
    __syncthreads();
    int c = cnt_s > 1 ? cnt_s : 1;
    out[g * EMB + threadIdx.x] = sums[g * EMB + threadIdx.x] / (float)c;
}

// ---------------------------------------------------------------------------
extern "C" void kernel_launch(void* const* d_in, const int* in_sizes, int n_in,
                              void* d_out, int out_size, void* d_ws, size_t ws_size,
                              hipStream_t stream) {
    const float* x    = (const float*)d_in[0];
    const float* ea   = (const float*)d_in[1];
    const int*   ei   = (const int*)d_in[2];
    const int*   batch= (const int*)d_in[3];
    const float* el1w = (const float*)d_in[4];
    const float* el1b = (const float*)d_in[5];
    const float* w1a  = (const float*)d_in[6];
    const float* b1a  = (const float*)d_in[7];
    const float* w1b  = (const float*)d_in[8];
    const float* b1b  = (const float*)d_in[9];
    const float* el2w = (const float*)d_in[10];
    const float* el2b = (const float*)d_in[11];
    const float* w2a  = (const float*)d_in[12];
    const float* b2a  = (const float*)d_in[13];
    const float* w2b  = (const float*)d_in[14];
    const float* b2b  = (const float*)d_in[15];

    char* ws = (char*)d_ws;
    short* aggout = (short*)ws;                       // [N][64] bf16, both layers (64,000,000 B)
    float* hbuf   = (float*)(ws + 64000000);          // [N][64] f32 (128,000,000 B)
    int*   csr_src= (int*)(ws + 192000000);           // [E] src (8,000,000 B)
    float* csr_ea = (float*)(ws + 200000064);         // [E][12] f32, CSR order (96,000,000 B)
    int*   rowptr = (int*)(ws + 296000128);           // N+1
    int*   cursor = (int*)(ws + 298000192);           // N
    int*   deg    = (int*)(ws + 300000192);           // N
    int*   bsum   = (int*)(ws + 302000192);           // NBLK
    int*   boff   = (int*)(ws + 302000704);           // NBLK
    float* sums   = (float*)(ws + 302001216);         // G*128 f32
    short* wts    = (short*)(ws + 310389824);         // 32768 shorts
    short* w1a_t = wts;
    short* w1b_t = wts + 4096;
    short* w2a_t = wts + 8192;
    short* w2b_t = wts + 16384;

    hipMemsetAsync(deg, 0, (size_t)NN * 4, stream);
    hipMemsetAsync(sums, 0, (size_t)GG * EMB * 4, stream);

    prep_weights<<<128, 256, 0, stream>>>(w1a, w1b, w2a, w2b, wts);
    // CSR build (+ attr reorder into CSR order)
    hist_kernel<<<(EE + 255) / 256, 256, 0, stream>>>(ei, deg);
    scan_reduce<<<NBLK, 256, 0, stream>>>(deg, bsum);
    scan_mid<<<1, 128, 0, stream>>>(bsum, boff, rowptr);
    scan_final<<<NBLK, 256, 0, stream>>>(deg, boff, rowptr, cursor);
    scatter_kernel<<<(EE + 255) / 256, 256, 0, stream>>>(ei, ea, cursor, csr_src, csr_ea);
    // Layer 1
    agg_gather<ND><<<NN / 32, 256, 0, stream>>>(x, csr_ea, el1w, el1b, rowptr, csr_src, aggout);
    mlp1<<<7813, 256, 0, stream>>>(aggout, w1a_t, b1a, w1b_t, b1b, hbuf);
    // Layer 2
    agg_gather<HH><<<NN / 32, 256, 0, stream>>>(hbuf, csr_ea, el2w, el2b, rowptr, csr_src, aggout);
    mlp2<<<7813, 256, 0, stream>>>(aggout, w2a_t, b2a, w2b_t, b2b, batch, sums);
    finalize<<<GG, 128, 0, stream>>>(sums, batch, (float*)d_out);
}

// Round 2
// 1007.026 us; speedup vs baseline: 1.2357x; 1.0605x over previous
//
#include <hip/hip_runtime.h>
#include <hip/hip_bf16.h>

#define NN 500000
#define EE 2000000
#define GG 16384
#define ND 44
#define ED 12
#define HH 64
#define EMB 128
#define NBLK 123          // ceil(NN / 4096) scan blocks
#define NTILE (NN / 16)   // 31250, exact

typedef __attribute__((ext_vector_type(8))) short bf16x8;
typedef __attribute__((ext_vector_type(4))) float f32x4;

// fp32 -> bf16 round-to-nearest-even, bit pattern as short
__device__ inline short f2bf(float v) {
    unsigned int x = __builtin_bit_cast(unsigned int, v);
    x += 0x7FFFu + ((x >> 16) & 1u);
    return (short)(x >> 16);
}

// Wave-local LDS ordering fence. All LDS buffers in the MLP kernels are
// private to ONE wave: the DS pipe is in-order per wave, so cross-wave
// s_barrier is unnecessary. We only need (a) the compiler not to reorder
// LDS ops across this point ("memory" clobber + sched_barrier) and (b) the
// read data to be waited on (lgkmcnt). Crucially this does NOT drain vmcnt,
// so global prefetches stay in flight across the transpose.
__device__ inline void wave_lds_fence() {
    asm volatile("s_waitcnt lgkmcnt(0)" ::: "memory");
    __builtin_amdgcn_sched_barrier(0);
}

// ---------------------------------------------------------------------------
// Weight prep: transpose to [n][k] layout, cast to bf16, zero-pad K of w1a to 64
__global__ __launch_bounds__(256) void prep_weights(
    const float* __restrict__ w1a, const float* __restrict__ w1b,
    const float* __restrict__ w2a, const float* __restrict__ w2b,
    short* __restrict__ o) {
    int t = blockIdx.x * 256 + threadIdx.x;
    if (t < 4096) {
        int n = t >> 6, k = t & 63;
        o[t] = f2bf(k < ND ? w1a[k * HH + n] : 0.f);
    } else if (t < 8192) {
        int u = t - 4096; int n = u >> 6, k = u & 63;
        o[t] = f2bf(w1b[k * HH + n]);
    } else if (t < 16384) {
        int u = t - 8192; int n = u >> 6, k = u & 63;
        o[t] = f2bf(w2a[k * EMB + n]);
    } else if (t < 32768) {
        int u = t - 16384; int n = u >> 7, k = u & 127;
        o[t] = f2bf(w2b[k * EMB + n]);
    }
}

// ---------------------------------------------------------------------------
// CSR build: histogram of dst, exclusive scan, scatter by dst.
__global__ __launch_bounds__(256) void hist_kernel(const int* __restrict__ ei,
                                                   int* __restrict__ deg) {
    int e = blockIdx.x * 256 + threadIdx.x;
    if (e < EE) atomicAdd(&deg[ei[EE + e]], 1);
}

__global__ __launch_bounds__(256) void scan_reduce(const int* __restrict__ deg,
                                                   int* __restrict__ bsum) {
    int b = blockIdx.x, t = threadIdx.x;
    int base = b * 4096;
    int s = 0;
    for (int i = t; i < 4096; i += 256) {
        int g = base + i;
        if (g < NN) s += deg[g];
    }
#pragma unroll
    for (int off = 32; off; off >>= 1) s += __shfl_xor(s, off);
    __shared__ int ws[4];
    if ((t & 63) == 0) ws[t >> 6] = s;
    __syncthreads();
    if (t == 0) bsum[b] = ws[0] + ws[1] + ws[2] + ws[3];
}

__global__ __launch_bounds__(128) void scan_mid(const int* __restrict__ bsum,
                                                int* __restrict__ boff,
                                                int* __restrict__ rowptr) {
    int t = threadIdx.x;
    int v = (t < NBLK) ? bsum[t] : 0;
    int x = v;
#pragma unroll
    for (int off = 1; off < 64; off <<= 1) {
        int y = __shfl_up(x, off);
        if ((t & 63) >= off) x += y;
    }
    __shared__ int wt[2];
    if ((t & 63) == 63) wt[t >> 6] = x;
    __syncthreads();
    int xx = x + ((t >= 64) ? wt[0] : 0);
    if (t < NBLK) boff[t] = xx - v;
    if (t == 127) rowptr[NN] = xx;
}

__global__ __launch_bounds__(256) void scan_final(const int* __restrict__ deg,
                                                  const int* __restrict__ boff,
                                                  int* __restrict__ rowptr,
                                                  int* __restrict__ cursor) {
    int b = blockIdx.x, t = threadIdx.x;
    int base = b * 4096 + t * 16;
    int loc[16];
    int s = 0;
#pragma unroll
    for (int j = 0; j < 16; ++j) {
        int g = base + j;
        loc[j] = (g < NN) ? deg[g] : 0;
        s += loc[j];
    }
    int xinc = s;
#pragma unroll
    for (int off = 1; off < 64; off <<= 1) {
        int y = __shfl_up(xinc, off);
        if ((t & 63) >= off) xinc += y;
    }
    __shared__ int wt[4];
    if ((t & 63) == 63) wt[t >> 6] = xinc;
    __syncthreads();
    int wv = t >> 6, woff = 0;
#pragma unroll
    for (int k = 0; k < 4; ++k)
        if (k < wv) woff += wt[k];
    int run = boff[b] + woff + (xinc - s);
#pragma unroll
    for (int j = 0; j < 16; ++j) {
        int g = base + j;
        if (g < NN) { rowptr[g] = run; cursor[g] = run; }
        run += loc[j];
    }
}

// Scatter: besides src, also reorder the 48B edge-attr row into CSR (dst-sorted)
// order so agg_gather reads attrs SEQUENTIALLY instead of random-by-eid.
__global__ __launch_bounds__(256) void scatter_kernel(const int* __restrict__ ei,
                                                      const float* __restrict__ ea,
                                                      int* __restrict__ cursor,
                                                      int* __restrict__ csr_src,
                                                      float* __restrict__ csr_ea) {
    int e = blockIdx.x * 256 + threadIdx.x;
    if (e < EE) {
        int dst = ei[EE + e];
        const float4* s = (const float4*)(ea + (size_t)e * ED);
        float4 a0 = s[0], a1 = s[1], a2 = s[2];
        int pos = atomicAdd(&cursor[dst], 1);
        csr_src[pos] = ei[e];
        float4* d = (float4*)(csr_ea + (size_t)pos * ED);
        d[0] = a0; d[1] = a1; d[2] = a2;
    }
}

// ---------------------------------------------------------------------------
// Gather aggregation, 8 nodes/wave, with FUSED skip-add + bf16 output:
//   out16[i][0:64] = bf16( xf[i] + sum_{e: dst=i} relu(xf[src] + ea@W + b) )
template <int D>
__global__ __launch_bounds__(256) void agg_gather(
    const float* __restrict__ xf, const float* __restrict__ cea,
    const float* __restrict__ ew, const float* __restrict__ eb,
    const int* __restrict__ rowptr, const int* __restrict__ csr_src,
    short* __restrict__ out) {
    int lane = threadIdx.x & 63;
    int wv = threadIdx.x >> 6;
    int i0 = (blockIdx.x * 4 + wv) * 8;
    if (i0 >= NN) return;
    float w0, w1, w2, w3, w4, w5, w6, w7, w8, w9, w10, w11, breg;
    if (D == 64 || lane < D) {
        w0 = ew[0 * D + lane];  w1 = ew[1 * D + lane];  w2 = ew[2 * D + lane];
        w3 = ew[3 * D + lane];  w4 = ew[4 * D + lane];  w5 = ew[5 * D + lane];
        w6 = ew[6 * D + lane];  w7 = ew[7 * D + lane];  w8 = ew[8 * D + lane];
        w9 = ew[9 * D + lane];  w10 = ew[10 * D + lane]; w11 = ew[11 * D + lane];
        breg = eb[lane];
    } else {
        w0=w1=w2=w3=w4=w5=w6=w7=w8=w9=w10=w11=0.f; breg = 0.f;
    }
    int rp = (lane <= 8) ? rowptr[i0 + lane] : 0;
    int beg = __builtin_amdgcn_readfirstlane(__builtin_amdgcn_readlane(rp, 0));
    int end = __builtin_amdgcn_readfirstlane(__builtin_amdgcn_readlane(rp, 8));
    // coalesced preload of this wave's CSR src span (first 128 entries)
    int s0 = 0, s1 = 0;
    if (beg + lane < end) s0 = csr_src[beg + lane];
    if (beg + 64 + lane < end) s1 = csr_src[beg + 64 + lane];

    auto SKIPLD = [&](int j) -> float {
        return (D == 64 || lane < D) ? xf[(size_t)(i0 + j) * D + lane] : 0.f;
    };

    float acc = 0.f;
    int np = 0;
    int nb = __builtin_amdgcn_readlane(rp, 1);
    float sk = SKIPLD(0);   // skip row for current node, prefetched early
    while (np < 8 && nb == beg) {
        out[(size_t)(i0 + np) * 64 + lane] = f2bf(sk);   // acc == 0
        ++np;
        nb = (np < 8) ? __builtin_amdgcn_readlane(rp, np + 1) : 0x7fffffff;
        sk = (np < 8) ? SKIPLD(np) : 0.f;
    }

    auto LOADE = [&](int pos, float4& E0, float4& E1, float4& E2, float& XV) {
        if (pos < end) {
            int off = pos - beg;
            int src;
            if (off < 64)       src = __builtin_amdgcn_readlane(s0, off);
            else if (off < 128) src = __builtin_amdgcn_readlane(s1, off - 64);
            else                src = __builtin_amdgcn_readfirstlane(csr_src[pos]);
            const float4* ep = (const float4*)(cea + (size_t)pos * ED);
            E0 = ep[0]; E1 = ep[1]; E2 = ep[2];
            if (D == 64) XV = xf[(size_t)src * D + lane];
            else         XV = (lane < D) ? xf[(size_t)src * D + lane] : 0.f;
        }
    };
    auto CONSUME = [&](int pos, const float4& E0, const float4& E1,
                       const float4& E2, float XV) {
        if (pos < end) {
            float elin = breg;
            elin = fmaf(E0.x, w0, elin);  elin = fmaf(E0.y, w1, elin);
            elin = fmaf(E0.z, w2, elin);  elin = fmaf(E0.w, w3, elin);
            elin = fmaf(E1.x, w4, elin);  elin = fmaf(E1.y, w5, elin);
            elin = fmaf(E1.z, w6, elin);  elin = fmaf(E1.w, w7, elin);
            elin = fmaf(E2.x, w8, elin);  elin = fmaf(E2.y, w9, elin);
            elin = fmaf(E2.z, w10, elin); elin = fmaf(E2.w, w11, elin);
            acc += fmaxf(XV + elin, 0.f);
            int p1 = pos + 1;
            if (p1 == nb) {
                do {
                    out[(size_t)(i0 + np) * 64 + lane] = f2bf(acc + sk);
                    acc = 0.f; ++np;
                    nb = (np < 8) ? __builtin_amdgcn_readlane(rp, np + 1) : 0x7fffffff;
                    sk = (np < 8) ? SKIPLD(np) : 0.f;
                } while (p1 == nb);
            }
        }
    };

    float4 A0, A1, A2, B0, B1, B2, C0, C1, C2, D0, D1, D2;
    float Ax = 0.f, Bx = 0.f, Cx = 0.f, Dx = 0.f;
    int base = beg;
    LOADE(base + 0, A0, A1, A2, Ax);
    LOADE(base + 1, B0, B1, B2, Bx);
    LOADE(base + 2, C0, C1, C2, Cx);
    LOADE(base + 3, D0, D1, D2, Dx);
    while (base < end) {
        CONSUME(base + 0, A0, A1, A2, Ax);
        CONSUME(base + 1, B0, B1, B2, Bx);
        LOADE(base + 4, A0, A1, A2, Ax);
        LOADE(base + 5, B0, B1, B2, Bx);
        if (base + 2 >= end) break;
        CONSUME(base + 2, C0, C1, C2, Cx);
        CONSUME(base + 3, D0, D1, D2, Dx);
        LOADE(base + 6, C0, C1, C2, Cx);
        LOADE(base + 7, D0, D1, D2, Dx);
        base += 4;
    }
}

// ---------------------------------------------------------------------------
// Node MLP 1: h = relu( relu(a @ w1a + b1a) @ w1b + b1b ), a = bf16[N][64] in.
// Persistent waves: weights live in VGPRs for the whole kernel; each wave
// grid-strides over 16-node tiles with the next tile's A-fragment prefetched.
// LDS buffer is PER-WAVE -> no __syncthreads anywhere (wave_lds_fence only).
#define HSTR1 68
__global__ __launch_bounds__(256, 3) void mlp1(
    const short* __restrict__ ain,
    const short* __restrict__ w1a_t, const float* __restrict__ b1a,
    const short* __restrict__ w1b_t, const float* __restrict__ b1b,
    float* __restrict__ h) {
    __shared__ float hid[4][16 * HSTR1];
    int lane = threadIdx.x & 63;
    int wv = threadIdx.x >> 6;
    int mrow = lane & 15, q = lane >> 4;
    float* hw = hid[wv];

    bf16x8 wa[4][2], wb[4][2];
    float ba[4], bb[4];
#pragma unroll
    for (int nt = 0; nt < 4; ++nt) {
        int n = nt * 16 + mrow;
        ba[nt] = b1a[n]; bb[nt] = b1b[n];
#pragma unroll
        for (int s = 0; s < 2; ++s) {
            wa[nt][s] = *(const bf16x8*)(w1a_t + n * 64 + s * 32 + q * 8);
            wb[nt][s] = *(const bf16x8*)(w1b_t + n * 64 + s * 32 + q * 8);
        }
    }

    int tile = blockIdx.x * 4 + wv;
    int stride = gridDim.x * 4;
    if (tile >= NTILE) return;
    bf16x8 a0 = *(const bf16x8*)(ain + (size_t)(tile * 16 + mrow) * 64 + q * 8);
    bf16x8 a1 = *(const bf16x8*)(ain + (size_t)(tile * 16 + mrow) * 64 + 32 + q * 8);
    while (true) {
        int nxt = tile + stride;
        bool more = nxt < NTILE;
        bf16x8 na0{}, na1{};
        if (more) {
            na0 = *(const bf16x8*)(ain + (size_t)(nxt * 16 + mrow) * 64 + q * 8);
            na1 = *(const bf16x8*)(ain + (size_t)(nxt * 16 + mrow) * 64 + 32 + q * 8);
        }
        int node0 = tile * 16;
#pragma unroll
        for (int nt = 0; nt < 4; ++nt) {
            f32x4 acc = {ba[nt], ba[nt], ba[nt], ba[nt]};
            acc = __builtin_amdgcn_mfma_f32_16x16x32_bf16(a0, wa[nt][0], acc, 0, 0, 0);
            acc = __builtin_amdgcn_mfma_f32_16x16x32_bf16(a1, wa[nt][1], acc, 0, 0, 0);
            int n = nt * 16 + mrow;
#pragma unroll
            for (int r = 0; r < 4; ++r)
                hw[(q * 4 + r) * HSTR1 + n] = fmaxf(acc[r], 0.f);
        }
        wave_lds_fence();
        bf16x8 af2[2];
#pragma unroll
        for (int s = 0; s < 2; ++s) {
            f32x4 v0 = *(const f32x4*)(hw + mrow * HSTR1 + s * 32 + q * 8);
            f32x4 v1 = *(const f32x4*)(hw + mrow * HSTR1 + s * 32 + q * 8 + 4);
#pragma unroll
            for (int j = 0; j < 4; ++j) { af2[s][j] = f2bf(v0[j]); af2[s][j + 4] = f2bf(v1[j]); }
        }
#pragma unroll
        for (int nt = 0; nt < 4; ++nt) {
            f32x4 acc = {bb[nt], bb[nt], bb[nt], bb[nt]};
            acc = __builtin_amdgcn_mfma_f32_16x16x32_bf16(af2[0], wb[nt][0], acc, 0, 0, 0);
            acc = __builtin_amdgcn_mfma_f32_16x16x32_bf16(af2[1], wb[nt][1], acc, 0, 0, 0);
            int n = nt * 16 + mrow;
#pragma unroll
            for (int r = 0; r < 4; ++r)
                h[(size_t)(node0 + q * 4 + r) * HH + n] = fmaxf(acc[r], 0.f);
        }
        if (!more) break;
        tile = nxt; a0 = na0; a1 = na1;
        wave_lds_fence();   // order this iter's hw reads vs next iter's writes
    }
}

// ---------------------------------------------------------------------------
// Node MLP 2 + fused mean-pool accumulate: input = bf16[N][64] (h+agg2 fused).
// Persistent waves, register-resident weights (w2a 64 + w2b 128 VGPR),
// per-wave LDS, no __syncthreads, A/batch prefetched one tile ahead.
#define HSTR2 132
__global__ __launch_bounds__(256, 2) void mlp2(
    const short* __restrict__ ain,
    const short* __restrict__ w2a_t, const float* __restrict__ b2a,
    const short* __restrict__ w2b_t, const float* __restrict__ b2b,
    const int* __restrict__ batch, float* __restrict__ sums) {
    __shared__ float buf[4][16 * HSTR2];
    int lane = threadIdx.x & 63;
    int wv = threadIdx.x >> 6;
    int mrow = lane & 15, q = lane >> 4;
    float* bw = buf[wv];

    bf16x8 wa[8][2], wb[8][4];
    float ba[8], bb[8];
#pragma unroll
    for (int nt = 0; nt < 8; ++nt) {
        int n = nt * 16 + mrow;
        ba[nt] = b2a[n]; bb[nt] = b2b[n];
#pragma unroll
        for (int s = 0; s < 2; ++s)
            wa[nt][s] = *(const bf16x8*)(w2a_t + n * HH + s * 32 + q * 8);
#pragma unroll
        for (int s = 0; s < 4; ++s)
            wb[nt][s] = *(const bf16x8*)(w2b_t + n * EMB + s * 32 + q * 8);
    }

    int tile = blockIdx.x * 4 + wv;
    int stride = gridDim.x * 4;
    if (tile >= NTILE) return;
    bf16x8 a0 = *(const bf16x8*)(ain + (size_t)(tile * 16 + mrow) * 64 + q * 8);
    bf16x8 a1 = *(const bf16x8*)(ain + (size_t)(tile * 16 + mrow) * 64 + 32 + q * 8);
    int bv = (lane < 16) ? batch[tile * 16 + lane] : 0;
    while (true) {
        int nxt = tile + stride;
        bool more = nxt < NTILE;
        bf16x8 na0{}, na1{};
        int nbv = 0;
        if (more) {
            na0 = *(const bf16x8*)(ain + (size_t)(nxt * 16 + mrow) * 64 + q * 8);
            na1 = *(const bf16x8*)(ain + (size_t)(nxt * 16 + mrow) * 64 + 32 + q * 8);
            nbv = (lane < 16) ? batch[nxt * 16 + lane] : 0;
        }
        // GEMM1: 64 -> 128, relu, to LDS (transpose staging)
#pragma unroll
        for (int nt = 0; nt < 8; ++nt) {
            f32x4 acc = {ba[nt], ba[nt], ba[nt], ba[nt]};
            acc = __builtin_amdgcn_mfma_f32_16x16x32_bf16(a0, wa[nt][0], acc, 0, 0, 0);
            acc = __builtin_amdgcn_mfma_f32_16x16x32_bf16(a1, wa[nt][1], acc, 0, 0, 0);
            int n = nt * 16 + mrow;
#pragma unroll
            for (int r = 0; r < 4; ++r)
                bw[(q * 4 + r) * HSTR2 + n] = fmaxf(acc[r], 0.f);
        }
        wave_lds_fence();
        bf16x8 af2[4];
#pragma unroll
        for (int s = 0; s < 4; ++s) {
            f32x4 v0 = *(const f32x4*)(bw + mrow * HSTR2 + s * 32 + q * 8);
            f32x4 v1 = *(const f32x4*)(bw + mrow * HSTR2 + s * 32 + q * 8 + 4);
#pragma unroll
            for (int j = 0; j < 4; ++j) { af2[s][j] = f2bf(v0[j]); af2[s][j + 4] = f2bf(v1[j]); }
        }
        // GEMM2: 128 -> 128, raw acc to LDS for pooling (in-order DS pipe makes
        // the read-before-overwrite within this wave safe without a barrier)
#pragma unroll
        for (int nt = 0; nt < 8; ++nt) {
            f32x4 acc = {bb[nt], bb[nt], bb[nt], bb[nt]};
#pragma unroll
            for (int s = 0; s < 4; ++s)
                acc = __builtin_amdgcn_mfma_f32_16x16x32_bf16(af2[s], wb[nt][s], acc, 0, 0, 0);
#pragma unroll
            for (int r = 0; r < 4; ++r)
                bw[(q * 4 + r) * HSTR2 + nt * 16 + mrow] = acc[r];
        }
        wave_lds_fence();
        // fused mean-pool accumulate (batch sorted -> few runs per tile)
#pragma unroll
        for (int cp = 0; cp < 2; ++cp) {
            int col = lane + cp * 64;
            float run = 0.f;
            int bprev = __shfl(bv, 0);
            for (int i = 0; i < 16; ++i) {
                int bg = __shfl(bv, i);
                if (bg != bprev) {
                    atomicAdd(&sums[bprev * EMB + col], run);
                    run = 0.f; bprev = bg;
                }
                run += bw[i * HSTR2 + col];
            }
            atomicAdd(&sums[bprev * EMB + col], run);
        }
        if (!more) break;
        tile = nxt; a0 = na0; a1 = na1; bv = nbv;
        wave_lds_fence();   // order pooling reads vs next iter's GEMM1 writes
    }
}

// ---------------------------------------------------------------------------
__global__ __launch_bounds__(128) void finalize(
    const float* __restrict__ sums, const int* __restrict__ batch,
    float* __restrict__ out) {
    int g = blockIdx.x;
    __shared__ int cnt_s;
    if (threadIdx.x == 0) {
        int lo = 0, hi = NN;
        while (lo < hi) { int mid = (lo + hi) >> 1; if (batch[mid] < g) lo = mid + 1; else hi = mid; }
        int lo2 = lo, hi2 = NN;
        while (lo2 < hi2) { int mid = (lo2 + hi2) >> 1; if (batch[mid] < g + 1) lo2 = mid + 1; else hi2 = mid; }
        cnt_s = lo2 - lo;
    }
    __syncthreads();
    int c = cnt_s > 1 ? cnt_s : 1;
    out[g * EMB + threadIdx.x] = sums[g * EMB + threadIdx.x] / (float)c;
}

// ---------------------------------------------------------------------------
extern "C" void kernel_launch(void* const* d_in, const int* in_sizes, int n_in,
                              void* d_out, int out_size, void* d_ws, size_t ws_size,
                              hipStream_t stream) {
    const float* x    = (const float*)d_in[0];
    const float* ea   = (const float*)d_in[1];
    const int*   ei   = (const int*)d_in[2];
    const int*   batch= (const int*)d_in[3];
    const float* el1w = (const float*)d_in[4];
    const float* el1b = (const float*)d_in[5];
    const float* w1a  = (const float*)d_in[6];
    const float* b1a  = (const float*)d_in[7];
    const float* w1b  = (const float*)d_in[8];
    const float* b1b  = (const float*)d_in[9];
    const float* el2w = (const float*)d_in[10];
    const float* el2b = (const float*)d_in[11];
    const float* w2a  = (const float*)d_in[12];
    const float* b2a  = (const float*)d_in[13];
    const float* w2b  = (const float*)d_in[14];
    const float* b2b  = (const float*)d_in[15];

    char* ws = (char*)d_ws;
    short* aggout = (short*)ws;                       // [N][64] bf16, both layers (64,000,000 B)
    float* hbuf   = (float*)(ws + 64000000);          // [N][64] f32 (128,000,000 B)
    int*   csr_src= (int*)(ws + 192000000);           // [E] src (8,000,000 B)
    float* csr_ea = (float*)(ws + 200000064);         // [E][12] f32, CSR order (96,000,000 B)
    int*   rowptr = (int*)(ws + 296000128);           // N+1
    int*   cursor = (int*)(ws + 298000192);           // N
    int*   deg    = (int*)(ws + 300000192);           // N
    int*   bsum   = (int*)(ws + 302000192);           // NBLK
    int*   boff   = (int*)(ws + 302000704);           // NBLK
    float* sums   = (float*)(ws + 302001216);         // G*128 f32
    short* wts    = (short*)(ws + 310389824);         // 32768 shorts
    short* w1a_t = wts;
    short* w1b_t = wts + 4096;
    short* w2a_t = wts + 8192;
    short* w2b_t = wts + 16384;

    hipMemsetAsync(deg, 0, (size_t)NN * 4, stream);
    hipMemsetAsync(sums, 0, (size_t)GG * EMB * 4, stream);

    prep_weights<<<128, 256, 0, stream>>>(w1a, w1b, w2a, w2b, wts);
    // CSR build (+ attr reorder into CSR order)
    hist_kernel<<<(EE + 255) / 256, 256, 0, stream>>>(ei, deg);
    scan_reduce<<<NBLK, 256, 0, stream>>>(deg, bsum);
    scan_mid<<<1, 128, 0, stream>>>(bsum, boff, rowptr);
    scan_final<<<NBLK, 256, 0, stream>>>(deg, boff, rowptr, cursor);
    scatter_kernel<<<(EE + 255) / 256, 256, 0, stream>>>(ei, ea, cursor, csr_src, csr_ea);
    // Layer 1
    agg_gather<ND><<<NN / 32, 256, 0, stream>>>(x, csr_ea, el1w, el1b, rowptr, csr_src, aggout);
    mlp1<<<1024, 256, 0, stream>>>(aggout, w1a_t, b1a, w1b_t, b1b, hbuf);
    // Layer 2
    agg_gather<HH><<<NN / 32, 256, 0, stream>>>(hbuf, csr_ea, el2w, el2b, rowptr, csr_src, aggout);
    mlp2<<<512, 256, 0, stream>>>(aggout, w2a_t, b2a, w2b_t, b2b, batch, sums);
    finalize<<<GG, 128, 0, stream>>>(sums, batch, (float*)d_out);
}